// Round 1
// baseline (3303.261 us; speedup 1.0000x reference)
//
#include <hip/hip_runtime.h>
#include <hip/hip_bf16.h>
#include <math.h>

#define E_N 200000
#define R_N 1000
#define D 128
#define NT 200000
#define NE (2*NT)
#define KDIM 300
#define BETA 0.3f
#define ALPHA_L 0.2f

// ---------------------------------------------------------------------------
// name_embed = embed[E,300] @ W[300,128] + b[128]
// block = 256 threads, computes 64 rows x 128 cols, K staged in chunks of 20
// ---------------------------------------------------------------------------
__global__ __launch_bounds__(256) void k_name_gemm(
    const float* __restrict__ A,    // [E][300]
    const float* __restrict__ W,    // [300][128]
    const float* __restrict__ b,    // [128]
    float* __restrict__ out)        // [E][128]
{
  __shared__ float At[20][65];    // transposed A tile, padded (bank spread)
  __shared__ float Wt[20][128];
  const int tid  = threadIdx.x;
  const int row0 = blockIdx.x * 64;
  const int c0   = (tid & 31) * 4;   // 4 output cols
  const int rg   = (tid >> 5) * 8;   // 8 output rows

  float acc[8][4];
#pragma unroll
  for (int i = 0; i < 8; i++)
#pragma unroll
    for (int j = 0; j < 4; j++) acc[i][j] = 0.f;

  for (int k0 = 0; k0 < KDIM; k0 += 20) {
    // stage A tile: 64 rows x 20 k = 1280 elems
#pragma unroll
    for (int i = 0; i < 5; i++) {
      int idx = i * 256 + tid;
      int r = idx / 20, k = idx % 20;
      At[k][r] = A[(size_t)(row0 + r) * KDIM + k0 + k];
    }
    // stage W tile: 20 x 128 = 2560 elems
#pragma unroll
    for (int i = 0; i < 10; i++) {
      int idx = i * 256 + tid;
      int k = idx >> 7, d = idx & 127;
      Wt[k][d] = W[(size_t)(k0 + k) * D + d];
    }
    __syncthreads();
#pragma unroll
    for (int k = 0; k < 20; k++) {
      float4 w4 = *(const float4*)&Wt[k][c0];
      float a[8];
#pragma unroll
      for (int i = 0; i < 8; i++) a[i] = At[k][rg + i];
#pragma unroll
      for (int i = 0; i < 8; i++) {
        acc[i][0] = fmaf(a[i], w4.x, acc[i][0]);
        acc[i][1] = fmaf(a[i], w4.y, acc[i][1]);
        acc[i][2] = fmaf(a[i], w4.z, acc[i][2]);
        acc[i][3] = fmaf(a[i], w4.w, acc[i][3]);
      }
    }
    __syncthreads();
  }
  float4 bb = *(const float4*)&b[c0];
#pragma unroll
  for (int i = 0; i < 8; i++) {
    float4 o;
    o.x = acc[i][0] + bb.x;
    o.y = acc[i][1] + bb.y;
    o.z = acc[i][2] + bb.z;
    o.w = acc[i][3] + bb.w;
    *(float4*)&out[(size_t)(row0 + rg + i) * D + c0] = o;
  }
}

// ---------------------------------------------------------------------------
// per-relation sums: sumH[r] += ent[h], sumT[r] += ent[t], cnt[r] += 1
// 32 lanes per triple, float4 per lane
// ---------------------------------------------------------------------------
__global__ __launch_bounds__(256) void k_rel_sum(
    const float* __restrict__ ent,
    const int* __restrict__ th, const int* __restrict__ tr,
    const int* __restrict__ tt,
    float* __restrict__ sumH, float* __restrict__ sumT,
    float* __restrict__ cnt)
{
  int g = blockIdx.x * 256 + threadIdx.x;
  int trip = g >> 5;
  int q = g & 31;
  if (trip >= NT) return;
  int h = th[trip], r = tr[trip], t = tt[trip];
  float4 eh = *(const float4*)&ent[(size_t)h * D + q * 4];
  float4 et = *(const float4*)&ent[(size_t)t * D + q * 4];
  float* sh = &sumH[(size_t)r * D + q * 4];
  atomicAdd(sh + 0, eh.x); atomicAdd(sh + 1, eh.y);
  atomicAdd(sh + 2, eh.z); atomicAdd(sh + 3, eh.w);
  float* st = &sumT[(size_t)r * D + q * 4];
  atomicAdd(st + 0, et.x); atomicAdd(st + 1, et.y);
  atomicAdd(st + 2, et.z); atomicAdd(st + 3, et.w);
  if (q == 0) atomicAdd(&cnt[r], 1.0f);
}

// ---------------------------------------------------------------------------
// per-relation: r1 = relu(sum/cnt) @ {wL,wR}; fold in w_att scaling
// aR[r][d] = relu((sumH[r]@wL)[d]/cnt) * watt[d]
// bR[r][d] = relu((sumT[r]@wR)[d]/cnt) * watt[128+d]
// one block per relation, 128 threads
// ---------------------------------------------------------------------------
__global__ __launch_bounds__(128) void k_rel_mix(
    const float* __restrict__ sumH, const float* __restrict__ sumT,
    const float* __restrict__ cnt,
    const float* __restrict__ wL, const float* __restrict__ wR,
    const float* __restrict__ watt,
    float* __restrict__ aR, float* __restrict__ bR)
{
  __shared__ float sh[128], st[128];
  int r = blockIdx.x;
  int d = threadIdx.x;
  sh[d] = sumH[(size_t)r * D + d];
  st[d] = sumT[(size_t)r * D + d];
  __syncthreads();
  float c = cnt[r];
  float inv = (c == 0.f) ? 0.f : 1.f / c;
  float dl = 0.f, dr = 0.f;
#pragma unroll 8
  for (int k = 0; k < D; k++) {
    dl = fmaf(sh[k], wL[k * D + d], dl);
    dr = fmaf(st[k], wR[k * D + d], dr);
  }
  float r1a = fmaxf(dl * inv, 0.f);
  float r1b = fmaxf(dr * inv, 0.f);
  aR[(size_t)r * D + d] = r1a * watt[d];
  bR[(size_t)r * D + d] = r1b * watt[D + d];
}

// ---------------------------------------------------------------------------
// edge attention + scatter. Edge e<NT: row=h,col=t; e>=NT: row=t,col=h.
// att = exp(-leaky(dot(ent[row],aR[rel]) + dot(ent[col],bR[rel])))
// e_out[row] += att*ent[col];  rowsum[row] += att
// 32 lanes per edge (2 edges/wave), float4 per lane
// ---------------------------------------------------------------------------
__global__ __launch_bounds__(256) void k_edge(
    const float* __restrict__ ent,
    const float* __restrict__ aR, const float* __restrict__ bR,
    const int* __restrict__ th, const int* __restrict__ tr,
    const int* __restrict__ tt,
    float* __restrict__ e_out, float* __restrict__ rowsum)
{
  int g = blockIdx.x * 256 + threadIdx.x;
  int e = g >> 5;
  int q = g & 31;
  if (e >= NE) return;
  bool fwd = (e < NT);
  int ti = fwd ? e : e - NT;
  int row = fwd ? th[ti] : tt[ti];
  int col = fwd ? tt[ti] : th[ti];
  int rel = tr[ti];
  float4 er = *(const float4*)&ent[(size_t)row * D + q * 4];
  float4 ec = *(const float4*)&ent[(size_t)col * D + q * 4];
  float4 a4 = *(const float4*)&aR[(size_t)rel * D + q * 4];
  float4 b4 = *(const float4*)&bR[(size_t)rel * D + q * 4];
  float p = er.x * a4.x + er.y * a4.y + er.z * a4.z + er.w * a4.w
          + ec.x * b4.x + ec.y * b4.y + ec.z * b4.z + ec.w * b4.w;
  // butterfly reduce across the 32 lanes of this edge (masks <=16 stay in half)
#pragma unroll
  for (int m = 16; m >= 1; m >>= 1) p += __shfl_xor(p, m, 64);
  float s = p;
  float l = (s >= 0.f) ? s : ALPHA_L * s;
  float att = expf(-l);
  float* eo = &e_out[(size_t)row * D + q * 4];
  atomicAdd(eo + 0, att * ec.x);
  atomicAdd(eo + 1, att * ec.y);
  atomicAdd(eo + 2, att * ec.z);
  atomicAdd(eo + 3, att * ec.w);
  if (q == 0) atomicAdd(&rowsum[row], att);
}

// ---------------------------------------------------------------------------
// gat = base + BETA * relu(e_out * safe_recip(rowsum)); float4 per thread
// (out may alias e_out — read-then-write same element is fine)
// ---------------------------------------------------------------------------
__global__ __launch_bounds__(256) void k_finalize(
    const float* __restrict__ base,
    const float* __restrict__ e_out,
    const float* __restrict__ rowsum,
    float* __restrict__ out)
{
  int g = blockIdx.x * 256 + threadIdx.x;      // one float4 per thread
  if (g >= E_N * D / 4) return;
  int v = g >> 5;
  float rs = rowsum[v];
  float inv = (rs == 0.f) ? 0.f : 1.f / rs;
  float4 e4 = *(const float4*)&e_out[(size_t)g * 4];
  float4 b4 = *(const float4*)&base[(size_t)g * 4];
  float4 o;
  o.x = b4.x + BETA * fmaxf(e4.x * inv, 0.f);
  o.y = b4.y + BETA * fmaxf(e4.y * inv, 0.f);
  o.z = b4.z + BETA * fmaxf(e4.z * inv, 0.f);
  o.w = b4.w + BETA * fmaxf(e4.w * inv, 0.f);
  *(float4*)&out[(size_t)g * 4] = o;
}

// ---------------------------------------------------------------------------
extern "C" void kernel_launch(void* const* d_in, const int* in_sizes, int n_in,
                              void* d_out, int out_size, void* d_ws, size_t ws_size,
                              hipStream_t stream)
{
  const float* embed = (const float*)d_in[0];
  const float* wname = (const float*)d_in[1];
  const float* bname = (const float*)d_in[2];
  const float* wL    = (const float*)d_in[3];
  const float* wR    = (const float*)d_in[4];
  const float* watt  = (const float*)d_in[5];
  const int*   th    = (const int*)d_in[6];
  const int*   tr    = (const int*)d_in[7];
  const int*   tt    = (const int*)d_in[8];
  float* out = (float*)d_out;

  char* ws = (char*)d_ws;
  size_t off = 0;
  auto alloc = [&](size_t bytes) -> void* {
    void* p = ws + off;
    off = (off + bytes + 255) & ~(size_t)255;
    return p;
  };
  float* name   = (float*)alloc((size_t)E_N * D * 4);
  float* gat1   = (float*)alloc((size_t)E_N * D * 4);
  float* sumH   = (float*)alloc((size_t)R_N * D * 4);
  float* sumT   = (float*)alloc((size_t)R_N * D * 4);
  float* cnt    = (float*)alloc((size_t)R_N * 4);
  float* aR     = (float*)alloc((size_t)R_N * D * 4);
  float* bR     = (float*)alloc((size_t)R_N * D * 4);
  float* rowsum = (float*)alloc((size_t)E_N * 4);
  float* e_out  = out;   // reuse d_out as the edge accumulator both layers

  k_name_gemm<<<E_N / 64, 256, 0, stream>>>(embed, wname, bname, name);

  for (int layer = 0; layer < 2; layer++) {
    const float* ent = (layer == 0) ? name : gat1;
    float* gat = (layer == 0) ? gat1 : out;

    hipMemsetAsync(sumH, 0, (size_t)R_N * D * 4, stream);
    hipMemsetAsync(sumT, 0, (size_t)R_N * D * 4, stream);
    hipMemsetAsync(cnt, 0, (size_t)R_N * 4, stream);
    k_rel_sum<<<NT * 32 / 256, 256, 0, stream>>>(ent, th, tr, tt, sumH, sumT, cnt);
    k_rel_mix<<<R_N, 128, 0, stream>>>(sumH, sumT, cnt, wL, wR, watt, aR, bR);

    hipMemsetAsync(e_out, 0, (size_t)E_N * D * 4, stream);
    hipMemsetAsync(rowsum, 0, (size_t)E_N * 4, stream);
    k_edge<<<NE * 32 / 256, 256, 0, stream>>>(ent, aR, bR, th, tr, tt, e_out, rowsum);
    k_finalize<<<E_N * D / 4 / 256, 256, 0, stream>>>(name, e_out, rowsum, gat);
  }
}

// Round 2
// 677.265 us; speedup vs baseline: 4.8774x; 4.8774x over previous
//
#include <hip/hip_runtime.h>
#include <hip/hip_bf16.h>
#include <math.h>

#define E_N 200000
#define R_N 1000
#define D 128
#define NT 200000
#define NE (2*NT)
#define KDIM 300
#define BETA 0.3f
#define ALPHA_L 0.2f
#define SCB 1024

// ---------------------------------------------------------------------------
// name_embed = embed[E,300] @ W[300,128] + b[128]
// ---------------------------------------------------------------------------
__global__ __launch_bounds__(256) void k_name_gemm(
    const float* __restrict__ A,    // [E][300]
    const float* __restrict__ W,    // [300][128]
    const float* __restrict__ b,    // [128]
    float* __restrict__ out)        // [E][128]
{
  __shared__ float At[20][65];
  __shared__ float Wt[20][128];
  const int tid  = threadIdx.x;
  const int row0 = blockIdx.x * 64;
  const int c0   = (tid & 31) * 4;
  const int rg   = (tid >> 5) * 8;

  float acc[8][4];
#pragma unroll
  for (int i = 0; i < 8; i++)
#pragma unroll
    for (int j = 0; j < 4; j++) acc[i][j] = 0.f;

  for (int k0 = 0; k0 < KDIM; k0 += 20) {
#pragma unroll
    for (int i = 0; i < 5; i++) {
      int idx = i * 256 + tid;
      int r = idx / 20, k = idx % 20;
      At[k][r] = A[(size_t)(row0 + r) * KDIM + k0 + k];
    }
#pragma unroll
    for (int i = 0; i < 10; i++) {
      int idx = i * 256 + tid;
      int k = idx >> 7, d = idx & 127;
      Wt[k][d] = W[(size_t)(k0 + k) * D + d];
    }
    __syncthreads();
#pragma unroll
    for (int k = 0; k < 20; k++) {
      float4 w4 = *(const float4*)&Wt[k][c0];
      float a[8];
#pragma unroll
      for (int i = 0; i < 8; i++) a[i] = At[k][rg + i];
#pragma unroll
      for (int i = 0; i < 8; i++) {
        acc[i][0] = fmaf(a[i], w4.x, acc[i][0]);
        acc[i][1] = fmaf(a[i], w4.y, acc[i][1]);
        acc[i][2] = fmaf(a[i], w4.z, acc[i][2]);
        acc[i][3] = fmaf(a[i], w4.w, acc[i][3]);
      }
    }
    __syncthreads();
  }
  float4 bb = *(const float4*)&b[c0];
#pragma unroll
  for (int i = 0; i < 8; i++) {
    float4 o;
    o.x = acc[i][0] + bb.x;
    o.y = acc[i][1] + bb.y;
    o.z = acc[i][2] + bb.z;
    o.w = acc[i][3] + bb.w;
    *(float4*)&out[(size_t)(row0 + rg + i) * D + c0] = o;
  }
}

// ---------------------------------------------------------------------------
// CSR build: histogram -> exclusive scan -> scatter (destructive on offsets;
// after scatter off[x] = inclusive scan, readers use off[x-1]..off[x])
// ---------------------------------------------------------------------------
__global__ __launch_bounds__(256) void k_hist(
    const int* __restrict__ th, const int* __restrict__ tr,
    const int* __restrict__ tt,
    int* __restrict__ relDeg, int* __restrict__ rowDeg)
{
  int i = blockIdx.x * 256 + threadIdx.x;
  if (i >= NT) return;
  atomicAdd(&relDeg[tr[i]], 1);
  atomicAdd(&rowDeg[th[i]], 1);
  atomicAdd(&rowDeg[tt[i]], 1);
}

// exclusive scan of in[0..n) -> out; per-block total to part[b] (if non-null)
__global__ __launch_bounds__(SCB) void k_scan_block(
    const int* __restrict__ in, int* __restrict__ out,
    int* __restrict__ part, int n)
{
  __shared__ int buf[SCB];
  int i = blockIdx.x * SCB + threadIdx.x;
  int v = (i < n) ? in[i] : 0;
  buf[threadIdx.x] = v;
  __syncthreads();
  for (int off = 1; off < SCB; off <<= 1) {
    int add = (threadIdx.x >= off) ? buf[threadIdx.x - off] : 0;
    __syncthreads();
    buf[threadIdx.x] += add;
    __syncthreads();
  }
  if (i < n) out[i] = buf[threadIdx.x] - v;   // exclusive
  if (threadIdx.x == SCB - 1 && part) part[blockIdx.x] = buf[SCB - 1];
}

__global__ __launch_bounds__(SCB) void k_scan_add(
    int* __restrict__ out, const int* __restrict__ part, int n)
{
  int i = blockIdx.x * SCB + threadIdx.x;
  if (i < n) out[i] += part[blockIdx.x];
}

__global__ __launch_bounds__(256) void k_scatter(
    const int* __restrict__ th, const int* __restrict__ tr,
    const int* __restrict__ tt,
    int* __restrict__ relOff, int* __restrict__ rowOff,
    int* __restrict__ relIdx, unsigned* __restrict__ edgeCR)
{
  int i = blockIdx.x * 256 + threadIdx.x;
  if (i >= NT) return;
  int h = th[i], r = tr[i], t = tt[i];
  int p = atomicAdd(&relOff[r], 1);
  relIdx[p] = i;
  int pf = atomicAdd(&rowOff[h], 1);
  edgeCR[pf] = (unsigned)t | ((unsigned)r << 18);   // row=h: col=t
  int pb = atomicAdd(&rowOff[t], 1);
  edgeCR[pb] = (unsigned)h | ((unsigned)r << 18);   // row=t: col=h
}

// ---------------------------------------------------------------------------
// per-relation: sum ent[h], ent[t] over the relation's triples (no atomics),
// then aR[r] = relu((sumH@wL)/cnt)*watt[0:128], bR likewise with wR/watt[128:]
// one block (256 thr) per relation
// ---------------------------------------------------------------------------
__global__ __launch_bounds__(256) void k_rel_fused(
    const float* __restrict__ ent,
    const int* __restrict__ th, const int* __restrict__ tt,
    const int* __restrict__ relIdx, const int* __restrict__ relOff,
    const float* __restrict__ wL, const float* __restrict__ wR,
    const float* __restrict__ watt,
    float* __restrict__ aR, float* __restrict__ bR)
{
  __shared__ float bufH[8][128];
  __shared__ float bufT[8][128];
  __shared__ float red[2][128];
  int r = blockIdx.x;
  int start = (r == 0) ? 0 : relOff[r - 1];
  int end   = relOff[r];
  int g = threadIdx.x >> 5, q = threadIdx.x & 31;

  float4 aH = {0.f, 0.f, 0.f, 0.f}, aT = {0.f, 0.f, 0.f, 0.f};
  for (int j = start + g; j < end; j += 8) {
    int i = relIdx[j];
    float4 eh = *(const float4*)&ent[(size_t)th[i] * D + q * 4];
    float4 et = *(const float4*)&ent[(size_t)tt[i] * D + q * 4];
    aH.x += eh.x; aH.y += eh.y; aH.z += eh.z; aH.w += eh.w;
    aT.x += et.x; aT.y += et.y; aT.z += et.z; aT.w += et.w;
  }
  *(float4*)&bufH[g][q * 4] = aH;
  *(float4*)&bufT[g][q * 4] = aT;
  __syncthreads();

  int side = threadIdx.x >> 7;        // wave-uniform
  int d = threadIdx.x & 127;
  float s = 0.f;
  if (side == 0) {
#pragma unroll
    for (int g2 = 0; g2 < 8; g2++) s += bufH[g2][d];
  } else {
#pragma unroll
    for (int g2 = 0; g2 < 8; g2++) s += bufT[g2][d];
  }
  red[side][d] = s;
  __syncthreads();

  int cntv = end - start;
  float inv = cntv ? 1.f / (float)cntv : 0.f;
  const float* w = side ? wR : wL;
  float acc = 0.f;
#pragma unroll 8
  for (int k = 0; k < D; k++) acc = fmaf(red[side][k], w[k * D + d], acc);
  float rv = fmaxf(acc * inv, 0.f);
  if (side == 0) aR[(size_t)r * D + d] = rv * watt[d];
  else           bR[(size_t)r * D + d] = rv * watt[D + d];
}

// ---------------------------------------------------------------------------
// fused edge attention + neighbor aggregation + finalize, CSR by row.
// one 32-lane group per row; no atomics; writes gat row directly.
// ---------------------------------------------------------------------------
__global__ __launch_bounds__(256) void k_row_edge(
    const float* __restrict__ ent, const float* __restrict__ base,
    const float* __restrict__ aR, const float* __restrict__ bR,
    const int* __restrict__ rowOff, const unsigned* __restrict__ edgeCR,
    float* __restrict__ gat)
{
  int gg = blockIdx.x * 256 + threadIdx.x;
  int row = gg >> 5;
  int q = gg & 31;
  if (row >= E_N) return;
  int start = (row == 0) ? 0 : rowOff[row - 1];
  int end   = rowOff[row];

  float4 er = *(const float4*)&ent[(size_t)row * D + q * 4];
  float4 acc = {0.f, 0.f, 0.f, 0.f};
  float rowsum = 0.f;

  for (int j = start; j < end; j++) {
    unsigned cr = edgeCR[j];
    int col = cr & 0x3FFFF;
    int rel = cr >> 18;
    float4 ec = *(const float4*)&ent[(size_t)col * D + q * 4];
    float4 a4 = *(const float4*)&aR[(size_t)rel * D + q * 4];
    float4 b4 = *(const float4*)&bR[(size_t)rel * D + q * 4];
    float p = er.x * a4.x + er.y * a4.y + er.z * a4.z + er.w * a4.w
            + ec.x * b4.x + ec.y * b4.y + ec.z * b4.z + ec.w * b4.w;
#pragma unroll
    for (int m = 16; m >= 1; m >>= 1) p += __shfl_xor(p, m, 64);
    float l = (p >= 0.f) ? p : ALPHA_L * p;
    float att = expf(-l);
    acc.x = fmaf(att, ec.x, acc.x);
    acc.y = fmaf(att, ec.y, acc.y);
    acc.z = fmaf(att, ec.z, acc.z);
    acc.w = fmaf(att, ec.w, acc.w);
    rowsum += att;
  }
  float inv = (rowsum == 0.f) ? 0.f : 1.f / rowsum;
  float4 b4 = *(const float4*)&base[(size_t)row * D + q * 4];
  float4 o;
  o.x = b4.x + BETA * fmaxf(acc.x * inv, 0.f);
  o.y = b4.y + BETA * fmaxf(acc.y * inv, 0.f);
  o.z = b4.z + BETA * fmaxf(acc.z * inv, 0.f);
  o.w = b4.w + BETA * fmaxf(acc.w * inv, 0.f);
  *(float4*)&gat[(size_t)row * D + q * 4] = o;
}

// ---------------------------------------------------------------------------
extern "C" void kernel_launch(void* const* d_in, const int* in_sizes, int n_in,
                              void* d_out, int out_size, void* d_ws, size_t ws_size,
                              hipStream_t stream)
{
  const float* embed = (const float*)d_in[0];
  const float* wname = (const float*)d_in[1];
  const float* bname = (const float*)d_in[2];
  const float* wL    = (const float*)d_in[3];
  const float* wR    = (const float*)d_in[4];
  const float* watt  = (const float*)d_in[5];
  const int*   th    = (const int*)d_in[6];
  const int*   tr    = (const int*)d_in[7];
  const int*   tt    = (const int*)d_in[8];
  float* out = (float*)d_out;

  char* ws = (char*)d_ws;
  size_t off = 0;
  auto alloc = [&](size_t bytes) -> void* {
    void* p = ws + off;
    off = (off + bytes + 255) & ~(size_t)255;
    return p;
  };
  float*    name   = (float*)alloc((size_t)E_N * D * 4);
  float*    gat1   = (float*)alloc((size_t)E_N * D * 4);
  float*    aR     = (float*)alloc((size_t)R_N * D * 4);
  float*    bR     = (float*)alloc((size_t)R_N * D * 4);
  int*      relDeg = (int*)alloc((size_t)R_N * 4);
  int*      relOff = (int*)alloc((size_t)R_N * 4);
  int*      rowDeg = (int*)alloc((size_t)E_N * 4);
  int*      rowOff = (int*)alloc((size_t)E_N * 4);
  int*      relIdx = (int*)alloc((size_t)NT * 4);
  unsigned* edgeCR = (unsigned*)alloc((size_t)NE * 4);
  int*      part   = (int*)alloc((size_t)256 * 4);

  // name embedding GEMM
  k_name_gemm<<<E_N / 64, 256, 0, stream>>>(embed, wname, bname, name);

  // CSR build (triples are layer-invariant; build once)
  hipMemsetAsync(relDeg, 0, (size_t)R_N * 4, stream);
  hipMemsetAsync(rowDeg, 0, (size_t)E_N * 4, stream);
  k_hist<<<(NT + 255) / 256, 256, 0, stream>>>(th, tr, tt, relDeg, rowDeg);
  k_scan_block<<<1, SCB, 0, stream>>>(relDeg, relOff, nullptr, R_N);
  int nblk = (E_N + SCB - 1) / SCB;   // 196
  k_scan_block<<<nblk, SCB, 0, stream>>>(rowDeg, rowOff, part, E_N);
  k_scan_block<<<1, SCB, 0, stream>>>(part, part, nullptr, nblk);
  k_scan_add<<<nblk, SCB, 0, stream>>>(rowOff, part, E_N);
  k_scatter<<<(NT + 255) / 256, 256, 0, stream>>>(th, tr, tt, relOff, rowOff,
                                                  relIdx, edgeCR);

  for (int layer = 0; layer < 2; layer++) {
    const float* ent = (layer == 0) ? name : gat1;
    float* gat = (layer == 0) ? gat1 : out;
    k_rel_fused<<<R_N, 256, 0, stream>>>(ent, th, tt, relIdx, relOff,
                                         wL, wR, watt, aR, bR);
    k_row_edge<<<(E_N * 32) / 256, 256, 0, stream>>>(ent, name, aR, bR,
                                                     rowOff, edgeCR, gat);
  }
}

// Round 3
// 467.120 us; speedup vs baseline: 7.0716x; 1.4499x over previous
//
#include <hip/hip_runtime.h>
#include <hip/hip_bf16.h>
#include <math.h>

#define E_N 200000
#define R_N 1000
#define D 128
#define NT 200000
#define NE (2*NT)
#define KDIM 300
#define KP 320          // K padded to 10 steps of 32
#define BETA 0.3f
#define ALPHA_L 0.2f
#define SCB 1024

typedef __attribute__((ext_vector_type(8))) short short8;
typedef __attribute__((ext_vector_type(4))) float f32x4v;

__device__ inline short bfc(float f) {
  __hip_bfloat16 b = __float2bfloat16(f);
  return *reinterpret_cast<short*>(&b);
}

// ---------------------------------------------------------------------------
// Pack W[300][128] -> bf16 fragment-order buffer, zero-padded to K=320.
// Element ((s*8+f)*64 + l)*8 + j  holds  W[s*32 + (l>>4)*8 + j][f*16 + (l&15)]
// so the GEMM's B-fragment ds_read is a linear lane*16B read (conflict-free)
// and the block's W staging is a linear 80KB copy.
// ---------------------------------------------------------------------------
__global__ __launch_bounds__(256) void k_prep_w(
    const float* __restrict__ W, short* __restrict__ WtG)
{
  int e = blockIdx.x * 256 + threadIdx.x;   // 40960 elements
  if (e >= D * KP) return;
  int j = e & 7;
  int l = (e >> 3) & 63;
  int fi = e >> 9;                 // 0..79 = s*8+f
  int s = fi >> 3, f = fi & 7;
  int k = s * 32 + (l >> 4) * 8 + j;
  int c = f * 16 + (l & 15);
  float v = (k < KDIM) ? W[(size_t)k * D + c] : 0.f;
  WtG[e] = bfc(v);
}

// ---------------------------------------------------------------------------
// name = A[E,300] @ W + b  via bf16 MFMA. Block 256thr/4 waves, tile 128x128,
// wave = 32 rows x 128 cols. A-frags loaded global->reg (f32) and converted.
// ---------------------------------------------------------------------------
__global__ __launch_bounds__(256) void k_name_mfma(
    const float* __restrict__ A, const short* __restrict__ WtG,
    const float* __restrict__ b, float* __restrict__ out)
{
  __shared__ short Wt[D * KP];    // 81920 B

  const int tid = threadIdx.x;
  {  // linear W stage (layout identical to global)
    const uint4* src = (const uint4*)WtG;
    uint4* dst = (uint4*)Wt;
#pragma unroll
    for (int i = 0; i < 20; i++) dst[i * 256 + tid] = src[i * 256 + tid];
  }
  __syncthreads();

  const int wid = tid >> 6;
  const int l   = tid & 63;
  const int lc  = l & 15;          // A row / B,C col within fragment
  const int kb  = l >> 4;          // k sub-block
  const int rowbase = blockIdx.x * 128 + wid * 32;

  float bv[8];
#pragma unroll
  for (int f = 0; f < 8; f++) bv[f] = b[f * 16 + lc];

  f32x4v acc[2][8];
#pragma unroll
  for (int rf = 0; rf < 2; rf++)
#pragma unroll
    for (int f = 0; f < 8; f++) acc[rf][f] = (f32x4v){0.f, 0.f, 0.f, 0.f};

  int r0 = rowbase + lc;
  int r1 = rowbase + 16 + lc;
  int rl0 = (r0 < E_N) ? r0 : (E_N - 1);
  int rl1 = (r1 < E_N) ? r1 : (E_N - 1);
  const float* pa0 = A + (size_t)rl0 * KDIM + kb * 8;
  const float* pa1 = A + (size_t)rl1 * KDIM + kb * 8;

  float4 c00 = *(const float4*)(pa0 + 0);
  float4 c01 = *(const float4*)(pa0 + 4);
  float4 c10 = *(const float4*)(pa1 + 0);
  float4 c11 = *(const float4*)(pa1 + 4);

#pragma unroll
  for (int s = 0; s < 10; s++) {
    float4 n00, n01, n10, n11;
    if (s < 9) {
      if (s == 8) {
        // tail step k0=288: valid k<300 only
        float4 z = {0.f, 0.f, 0.f, 0.f};
        n00 = (kb <= 1) ? *(const float4*)(pa0 + 288) : z;  // 288..299
        n01 = (kb == 0) ? *(const float4*)(pa0 + 292) : z;  // 292..295
        n10 = (kb <= 1) ? *(const float4*)(pa1 + 288) : z;
        n11 = (kb == 0) ? *(const float4*)(pa1 + 292) : z;
      } else {
        int k = 32 * (s + 1);
        n00 = *(const float4*)(pa0 + k);
        n01 = *(const float4*)(pa0 + k + 4);
        n10 = *(const float4*)(pa1 + k);
        n11 = *(const float4*)(pa1 + k + 4);
      }
    }
    short8 af0, af1;
    af0[0] = bfc(c00.x); af0[1] = bfc(c00.y); af0[2] = bfc(c00.z); af0[3] = bfc(c00.w);
    af0[4] = bfc(c01.x); af0[5] = bfc(c01.y); af0[6] = bfc(c01.z); af0[7] = bfc(c01.w);
    af1[0] = bfc(c10.x); af1[1] = bfc(c10.y); af1[2] = bfc(c10.z); af1[3] = bfc(c10.w);
    af1[4] = bfc(c11.x); af1[5] = bfc(c11.y); af1[6] = bfc(c11.z); af1[7] = bfc(c11.w);
#pragma unroll
    for (int f = 0; f < 8; f++) {
      const short8 bf = *(const short8*)((const char*)Wt + (((s * 8 + f) << 6) + l) * 16);
      acc[0][f] = __builtin_amdgcn_mfma_f32_16x16x32_bf16(af0, bf, acc[0][f], 0, 0, 0);
      acc[1][f] = __builtin_amdgcn_mfma_f32_16x16x32_bf16(af1, bf, acc[1][f], 0, 0, 0);
    }
    c00 = n00; c01 = n01; c10 = n10; c11 = n11;
  }

  // epilogue: C layout col = lane&15, row = kb*4 + i
#pragma unroll
  for (int rf = 0; rf < 2; rf++) {
#pragma unroll
    for (int i = 0; i < 4; i++) {
      int row = rowbase + rf * 16 + kb * 4 + i;
      if (row < E_N) {
#pragma unroll
        for (int f = 0; f < 8; f++)
          out[(size_t)row * D + f * 16 + lc] = acc[rf][f][i] + bv[f];
      }
    }
  }
}

// ---------------------------------------------------------------------------
// CSR build: histogram -> exclusive scan -> scatter
// ---------------------------------------------------------------------------
__global__ __launch_bounds__(256) void k_hist(
    const int* __restrict__ th, const int* __restrict__ tr,
    const int* __restrict__ tt,
    int* __restrict__ relDeg, int* __restrict__ rowDeg)
{
  int i = blockIdx.x * 256 + threadIdx.x;
  if (i >= NT) return;
  atomicAdd(&relDeg[tr[i]], 1);
  atomicAdd(&rowDeg[th[i]], 1);
  atomicAdd(&rowDeg[tt[i]], 1);
}

__global__ __launch_bounds__(SCB) void k_scan_block(
    const int* __restrict__ in, int* __restrict__ out,
    int* __restrict__ part, int n)
{
  __shared__ int buf[SCB];
  int i = blockIdx.x * SCB + threadIdx.x;
  int v = (i < n) ? in[i] : 0;
  buf[threadIdx.x] = v;
  __syncthreads();
  for (int off = 1; off < SCB; off <<= 1) {
    int add = (threadIdx.x >= off) ? buf[threadIdx.x - off] : 0;
    __syncthreads();
    buf[threadIdx.x] += add;
    __syncthreads();
  }
  if (i < n) out[i] = buf[threadIdx.x] - v;
  if (threadIdx.x == SCB - 1 && part) part[blockIdx.x] = buf[SCB - 1];
}

__global__ __launch_bounds__(SCB) void k_scan_add(
    int* __restrict__ out, const int* __restrict__ part, int n)
{
  int i = blockIdx.x * SCB + threadIdx.x;
  if (i < n) out[i] += part[blockIdx.x];
}

__global__ __launch_bounds__(256) void k_scatter(
    const int* __restrict__ th, const int* __restrict__ tr,
    const int* __restrict__ tt,
    int* __restrict__ relOff, int* __restrict__ rowOff,
    int* __restrict__ relIdx, unsigned* __restrict__ edgeCR)
{
  int i = blockIdx.x * 256 + threadIdx.x;
  if (i >= NT) return;
  int h = th[i], r = tr[i], t = tt[i];
  int p = atomicAdd(&relOff[r], 1);
  relIdx[p] = i;
  int pf = atomicAdd(&rowOff[h], 1);
  edgeCR[pf] = (unsigned)t | ((unsigned)r << 18);
  int pb = atomicAdd(&rowOff[t], 1);
  edgeCR[pb] = (unsigned)h | ((unsigned)r << 18);
}

// ---------------------------------------------------------------------------
// per-relation sums + mix GEMM (no atomics); one block per relation
// ---------------------------------------------------------------------------
__global__ __launch_bounds__(256) void k_rel_fused(
    const float* __restrict__ ent,
    const int* __restrict__ th, const int* __restrict__ tt,
    const int* __restrict__ relIdx, const int* __restrict__ relOff,
    const float* __restrict__ wL, const float* __restrict__ wR,
    const float* __restrict__ watt,
    float* __restrict__ aR, float* __restrict__ bR)
{
  __shared__ float bufH[8][128];
  __shared__ float bufT[8][128];
  __shared__ float red[2][128];
  int r = blockIdx.x;
  int start = (r == 0) ? 0 : relOff[r - 1];
  int end   = relOff[r];
  int g = threadIdx.x >> 5, q = threadIdx.x & 31;

  float4 aH = {0.f, 0.f, 0.f, 0.f}, aT = {0.f, 0.f, 0.f, 0.f};
  for (int j = start + g; j < end; j += 8) {
    int i = relIdx[j];
    float4 eh = *(const float4*)&ent[(size_t)th[i] * D + q * 4];
    float4 et = *(const float4*)&ent[(size_t)tt[i] * D + q * 4];
    aH.x += eh.x; aH.y += eh.y; aH.z += eh.z; aH.w += eh.w;
    aT.x += et.x; aT.y += et.y; aT.z += et.z; aT.w += et.w;
  }
  *(float4*)&bufH[g][q * 4] = aH;
  *(float4*)&bufT[g][q * 4] = aT;
  __syncthreads();

  int side = threadIdx.x >> 7;
  int d = threadIdx.x & 127;
  float s = 0.f;
  if (side == 0) {
#pragma unroll
    for (int g2 = 0; g2 < 8; g2++) s += bufH[g2][d];
  } else {
#pragma unroll
    for (int g2 = 0; g2 < 8; g2++) s += bufT[g2][d];
  }
  red[side][d] = s;
  __syncthreads();

  int cntv = end - start;
  float inv = cntv ? 1.f / (float)cntv : 0.f;
  const float* w = side ? wR : wL;
  float acc = 0.f;
#pragma unroll 8
  for (int k = 0; k < D; k++) acc = fmaf(red[side][k], w[k * D + d], acc);
  float rv = fmaxf(acc * inv, 0.f);
  if (side == 0) aR[(size_t)r * D + d] = rv * watt[d];
  else           bR[(size_t)r * D + d] = rv * watt[D + d];
}

// ---------------------------------------------------------------------------
// fused edge attention + aggregation + finalize, CSR by row; no atomics
// ---------------------------------------------------------------------------
__global__ __launch_bounds__(256) void k_row_edge(
    const float* __restrict__ ent, const float* __restrict__ base,
    const float* __restrict__ aR, const float* __restrict__ bR,
    const int* __restrict__ rowOff, const unsigned* __restrict__ edgeCR,
    float* __restrict__ gat)
{
  int gg = blockIdx.x * 256 + threadIdx.x;
  int row = gg >> 5;
  int q = gg & 31;
  if (row >= E_N) return;
  int start = (row == 0) ? 0 : rowOff[row - 1];
  int end   = rowOff[row];

  float4 er = *(const float4*)&ent[(size_t)row * D + q * 4];
  float4 acc = {0.f, 0.f, 0.f, 0.f};
  float rowsum = 0.f;

  for (int j = start; j < end; j++) {
    unsigned cr = edgeCR[j];
    int col = cr & 0x3FFFF;
    int rel = cr >> 18;
    float4 ec = *(const float4*)&ent[(size_t)col * D + q * 4];
    float4 a4 = *(const float4*)&aR[(size_t)rel * D + q * 4];
    float4 b4 = *(const float4*)&bR[(size_t)rel * D + q * 4];
    float p = er.x * a4.x + er.y * a4.y + er.z * a4.z + er.w * a4.w
            + ec.x * b4.x + ec.y * b4.y + ec.z * b4.z + ec.w * b4.w;
#pragma unroll
    for (int m = 16; m >= 1; m >>= 1) p += __shfl_xor(p, m, 64);
    float lk = (p >= 0.f) ? p : ALPHA_L * p;
    float att = expf(-lk);
    acc.x = fmaf(att, ec.x, acc.x);
    acc.y = fmaf(att, ec.y, acc.y);
    acc.z = fmaf(att, ec.z, acc.z);
    acc.w = fmaf(att, ec.w, acc.w);
    rowsum += att;
  }
  float inv = (rowsum == 0.f) ? 0.f : 1.f / rowsum;
  float4 b4 = *(const float4*)&base[(size_t)row * D + q * 4];
  float4 o;
  o.x = b4.x + BETA * fmaxf(acc.x * inv, 0.f);
  o.y = b4.y + BETA * fmaxf(acc.y * inv, 0.f);
  o.z = b4.z + BETA * fmaxf(acc.z * inv, 0.f);
  o.w = b4.w + BETA * fmaxf(acc.w * inv, 0.f);
  *(float4*)&gat[(size_t)row * D + q * 4] = o;
}

// ---------------------------------------------------------------------------
extern "C" void kernel_launch(void* const* d_in, const int* in_sizes, int n_in,
                              void* d_out, int out_size, void* d_ws, size_t ws_size,
                              hipStream_t stream)
{
  const float* embed = (const float*)d_in[0];
  const float* wname = (const float*)d_in[1];
  const float* bname = (const float*)d_in[2];
  const float* wL    = (const float*)d_in[3];
  const float* wR    = (const float*)d_in[4];
  const float* watt  = (const float*)d_in[5];
  const int*   th    = (const int*)d_in[6];
  const int*   tr    = (const int*)d_in[7];
  const int*   tt    = (const int*)d_in[8];
  float* out = (float*)d_out;

  char* ws = (char*)d_ws;
  size_t off = 0;
  auto alloc = [&](size_t bytes) -> void* {
    void* p = ws + off;
    off = (off + bytes + 255) & ~(size_t)255;
    return p;
  };
  float*    name   = (float*)alloc((size_t)E_N * D * 4);
  float*    gat1   = (float*)alloc((size_t)E_N * D * 4);
  float*    aR     = (float*)alloc((size_t)R_N * D * 4);
  float*    bR     = (float*)alloc((size_t)R_N * D * 4);
  int*      relDeg = (int*)alloc((size_t)R_N * 4);
  int*      relOff = (int*)alloc((size_t)R_N * 4);
  int*      rowDeg = (int*)alloc((size_t)E_N * 4);
  int*      rowOff = (int*)alloc((size_t)E_N * 4);
  int*      relIdx = (int*)alloc((size_t)NT * 4);
  unsigned* edgeCR = (unsigned*)alloc((size_t)NE * 4);
  int*      part   = (int*)alloc((size_t)256 * 4);
  short*    WtG    = (short*)alloc((size_t)D * KP * 2);

  // name embedding GEMM (bf16 MFMA)
  k_prep_w<<<(D * KP + 255) / 256, 256, 0, stream>>>(wname, WtG);
  k_name_mfma<<<(E_N + 127) / 128, 256, 0, stream>>>(embed, WtG, bname, name);

  // CSR build (triples are layer-invariant)
  hipMemsetAsync(relDeg, 0, (size_t)R_N * 4, stream);
  hipMemsetAsync(rowDeg, 0, (size_t)E_N * 4, stream);
  k_hist<<<(NT + 255) / 256, 256, 0, stream>>>(th, tr, tt, relDeg, rowDeg);
  k_scan_block<<<1, SCB, 0, stream>>>(relDeg, relOff, nullptr, R_N);
  int nblk = (E_N + SCB - 1) / SCB;
  k_scan_block<<<nblk, SCB, 0, stream>>>(rowDeg, rowOff, part, E_N);
  k_scan_block<<<1, SCB, 0, stream>>>(part, part, nullptr, nblk);
  k_scan_add<<<nblk, SCB, 0, stream>>>(rowOff, part, E_N);
  k_scatter<<<(NT + 255) / 256, 256, 0, stream>>>(th, tr, tt, relOff, rowOff,
                                                  relIdx, edgeCR);

  for (int layer = 0; layer < 2; layer++) {
    const float* ent = (layer == 0) ? name : gat1;
    float* gat = (layer == 0) ? gat1 : out;
    k_rel_fused<<<R_N, 256, 0, stream>>>(ent, th, tt, relIdx, relOff,
                                         wL, wR, watt, aR, bR);
    k_row_edge<<<(E_N * 32) / 256, 256, 0, stream>>>(ent, name, aR, bR,
                                                     rowOff, edgeCR, gat);
  }
}